// Round 8
// baseline (456.550 us; speedup 1.0000x reference)
//
#include <hip/hip_runtime.h>
#include <hip/hip_bf16.h>

// ComparatorNBit: A,B are [N,32] float32 in {0,1}, MSB first.
// a_eq_b = all bits equal; a_gt_b = unsigned compare of packed 32-bit words.
//
// R8 = R7 (nontemporal loads/stores — WIN, 134->114 us inferred: L1/L2
// allocation churn was throttling the read stream) + 2 float4s/thread
// (R3 layout, 4 independent nt loads in flight). Re-test MLP now that the
// allocation-pressure throttle is gone: under the revised model deeper
// per-wave MLP can push reads from ~4.5 toward ~5.5-6 TB/s.
// Prediction: total ~435-443 if queue freshness binds; neutral => nt-read
// ceiling confirmed -> roofline at ~114 us kernel.

typedef float vfloat4 __attribute__((ext_vector_type(4)));

__global__ void __launch_bounds__(256)
comparator_kernel(const vfloat4* __restrict__ A, const vfloat4* __restrict__ B,
                  float* __restrict__ out_gt, float* __restrict__ out_eq) {
    const int tid = threadIdx.x;
    const long long base = (long long)blockIdx.x * 512 + tid;

    // 4 independent nt loads in flight.
    vfloat4 a0 = __builtin_nontemporal_load(&A[base]);
    vfloat4 b0 = __builtin_nontemporal_load(&B[base]);
    vfloat4 a1 = __builtin_nontemporal_load(&A[base + 256]);
    vfloat4 b1 = __builtin_nontemporal_load(&B[base + 256]);

#define PACK(v) (((unsigned)((v).x > 0.5f) << 3) | ((unsigned)((v).y > 0.5f) << 2) | \
                 ((unsigned)((v).z > 0.5f) << 1) |  (unsigned)((v).w > 0.5f))
    unsigned an0 = PACK(a0), bn0 = PACK(b0);
    unsigned an1 = PACK(a1), bn1 = PACK(b1);
#undef PACK

    // Wave-wide nibble-compare masks; byte g = row g's 8 nibble results,
    // bit k within the byte = nibble k (k=0 most significant).
    unsigned long long d0 = __ballot(an0 != bn0);
    unsigned long long t0 = __ballot(an0 > bn0);
    unsigned long long d1 = __ballot(an1 != bn1);
    unsigned long long t1 = __ballot(an1 > bn1);

    const int lane = tid & 63;
    if (lane < 16) {
        const int g = lane & 7;
        const bool second = lane >= 8;
        unsigned long long d = second ? d1 : d0;
        unsigned long long t = second ? t1 : t0;
        unsigned db = (unsigned)(d >> (8 * g)) & 0xFFu;
        unsigned tb = (unsigned)(t >> (8 * g)) & 0xFFu;

        // wave chunk0 first vec = blockIdx*512 + (tid & 192); row = vec/8.
        const long long row =
            (((long long)blockIdx.x * 512 + (tid & 192)) >> 3) + g + (second ? 32 : 0);

        unsigned msdiff = db & (0u - db);            // lowest set bit
        __builtin_nontemporal_store((tb & msdiff) ? 1.0f : 0.0f, &out_gt[row]);
        __builtin_nontemporal_store((db == 0u)   ? 1.0f : 0.0f, &out_eq[row]);
    }
}

extern "C" void kernel_launch(void* const* d_in, const int* in_sizes, int n_in,
                              void* d_out, int out_size, void* d_ws, size_t ws_size,
                              hipStream_t stream) {
    const vfloat4* A = (const vfloat4*)d_in[0];
    const vfloat4* B = (const vfloat4*)d_in[1];
    float* out = (float*)d_out;

    const int BITS = 32;
    long long n = in_sizes[0] / BITS;      // 2,000,000 rows

    float* out_gt = out;                   // output 0: a_gt_b [N]
    float* out_eq = out + n;               // output 1: a_eq_b [N]

    long long totalVec = n * 8;            // 16,000,000 float4s per input
    long long grid = totalVec / 512;       // 31,250 blocks, exact
    comparator_kernel<<<(int)grid, 256, 0, stream>>>(A, B, out_gt, out_eq);
}